// Round 2
// baseline (878.761 us; speedup 1.0000x reference)
//
#include <hip/hip_runtime.h>
#include <hip/hip_bf16.h>

#define B_ 2
#define L_ 4096
#define DM_ 512
#define H_ 8
#define DH_ 64
#define M_ 266
#define CK_ 64
#define NCHUNK_ 64          // L_/CK_
#define BH_ 16              // B_*H_
#define MT_ 17              // ceil(M_/16)

// ---------------------------------------------------------------------------
// C = X @ W^T + bias, X [rows,512] rm, W [512,512] rm.
// mode 0: out[r*512 + n] = v*scale
// mode 1: out[((b*H+h)*L + l)*64 + dh] = v*scale   (r = b*L+l, n = h*64+dh)
// ---------------------------------------------------------------------------
__global__ __launch_bounds__(256) void gemm_xwt(
    const float* __restrict__ X, const float* __restrict__ W,
    const float* __restrict__ bias, float* __restrict__ out,
    int mode, float scale)
{
    __shared__ float Xs[16][64];
    __shared__ float Ws[16][64];
    const int m0 = blockIdx.x * 64, n0 = blockIdx.y * 64;
    const int t = threadIdx.x;
    const int tm = t >> 4, tn = t & 15;
    const int lr = t >> 2, kq = (t & 3) << 2;
    float acc[4][4] = {};
    const float* xp = X + (size_t)(m0 + lr) * DM_ + kq;
    const float* wp = W + (size_t)(n0 + lr) * DM_ + kq;
    for (int kk = 0; kk < DM_; kk += 16) {
        float4 xv = *(const float4*)(xp + kk);
        float4 wv = *(const float4*)(wp + kk);
        __syncthreads();
        Xs[kq+0][lr] = xv.x; Xs[kq+1][lr] = xv.y; Xs[kq+2][lr] = xv.z; Xs[kq+3][lr] = xv.w;
        Ws[kq+0][lr] = wv.x; Ws[kq+1][lr] = wv.y; Ws[kq+2][lr] = wv.z; Ws[kq+3][lr] = wv.w;
        __syncthreads();
        #pragma unroll
        for (int k = 0; k < 16; ++k) {
            float4 a = *(const float4*)&Xs[k][tm << 2];
            float4 b = *(const float4*)&Ws[k][tn << 2];
            float av[4] = {a.x, a.y, a.z, a.w};
            float bb[4] = {b.x, b.y, b.z, b.w};
            #pragma unroll
            for (int i = 0; i < 4; ++i)
                #pragma unroll
                for (int j = 0; j < 4; ++j)
                    acc[i][j] += av[i] * bb[j];
        }
    }
    float4 bv = *(const float4*)&bias[n0 + (tn << 2)];
    float bb[4] = {bv.x, bv.y, bv.z, bv.w};
    #pragma unroll
    for (int i = 0; i < 4; ++i) {
        int r = m0 + (tm << 2) + i;
        float4 o;
        o.x = (acc[i][0] + bb[0]) * scale;
        o.y = (acc[i][1] + bb[1]) * scale;
        o.z = (acc[i][2] + bb[2]) * scale;
        o.w = (acc[i][3] + bb[3]) * scale;
        if (mode == 0) {
            *(float4*)&out[(size_t)r * DM_ + n0 + (tn << 2)] = o;
        } else {
            int b = r >> 12, l = r & (L_ - 1);
            int h = n0 >> 6;
            *(float4*)&out[(((size_t)(b * H_ + h)) * L_ + l) * DH_ + (tn << 2)] = o;
        }
    }
}

// ---------------------------------------------------------------------------
// Per (chunk c, bh): S_c[m][d] = sum_l k'[l][m] v[l][d], z_c[m] = sum_l k'[l][m]
// k'[l][m] = exp(-0.5||k_l||^2 + rf[m]·k_l)
// ---------------------------------------------------------------------------
__global__ __launch_bounds__(256) void chunk_sums(
    const float* __restrict__ Kh, const float* __restrict__ Vh,
    const float* __restrict__ RF,
    float* __restrict__ Sc, float* __restrict__ Zc)
{
    __shared__ float sKt[64 * 64];   // K^T [d][l]
    __shared__ float sV[64 * 64];    // V   [l][d]
    __shared__ float skp[16 * 64];   // k' tile [mm][l]
    __shared__ float sRF[16 * 64];   // RF tile [mm][d]
    __shared__ float shk[64];
    const int c = blockIdx.x, bh = blockIdx.y;
    const int t = threadIdx.x;
    const size_t chunkBase = ((size_t)bh * L_ + (size_t)c * CK_) * DH_;
    for (int u = t; u < 1024; u += 256) {
        float4 kv = *(const float4*)&Kh[chunkBase + (size_t)u * 4];
        int l = u >> 4, d0 = (u & 15) << 2;
        sKt[(d0+0)*64 + l] = kv.x; sKt[(d0+1)*64 + l] = kv.y;
        sKt[(d0+2)*64 + l] = kv.z; sKt[(d0+3)*64 + l] = kv.w;
        float4 vv = *(const float4*)&Vh[chunkBase + (size_t)u * 4];
        *(float4*)&sV[u * 4] = vv;
    }
    __syncthreads();
    if (t < 64) {
        float s = 0.f;
        for (int d = 0; d < 64; ++d) { float v = sKt[d*64 + t]; s += v * v; }
        shk[t] = -0.5f * s;
    }
    const size_t scBase = ((size_t)(c * BH_ + bh)) * M_ * DH_;
    const size_t zcBase = ((size_t)(c * BH_ + bh)) * M_;
    for (int mt = 0; mt < MT_; ++mt) {
        const int mbase = mt * 16;
        __syncthreads();
        {
            int mm = t >> 4, d0 = (t & 15) << 2;
            int m = mbase + mm;
            float4 rv = (m < M_) ? *(const float4*)&RF[(size_t)m * DH_ + d0]
                                 : make_float4(0.f, 0.f, 0.f, 0.f);
            *(float4*)&sRF[mm * 64 + d0] = rv;
        }
        __syncthreads();
        {
            int l = t & 63, mg = t >> 6;
            float dk[4] = {};
            for (int d = 0; d < 64; ++d) {
                float kv = sKt[d*64 + l];
                #pragma unroll
                for (int j = 0; j < 4; ++j)
                    dk[j] += sRF[(mg*4 + j)*64 + d] * kv;
            }
            #pragma unroll
            for (int j = 0; j < 4; ++j) {
                int mm = mg*4 + j, m = mbase + mm;
                skp[mm*64 + l] = (m < M_) ? __expf(shk[l] + dk[j]) : 0.f;
            }
        }
        __syncthreads();
        {
            int d = t & 63, mg = t >> 6;
            #pragma unroll
            for (int j = 0; j < 4; ++j) {
                int mm = mg*4 + j, m = mbase + mm;
                float acc = 0.f;
                for (int l = 0; l < 64; ++l)
                    acc += skp[mm*64 + l] * sV[l*64 + d];
                if (m < M_) Sc[scBase + (size_t)m * DH_ + d] = acc;
            }
            if (t < 16) {
                int m = mbase + t;
                if (m < M_) {
                    float zs = 0.f;
                    for (int l = 0; l < 64; ++l) zs += skp[t*64 + l];
                    Zc[zcBase + m] = zs;
                }
            }
        }
    }
}

// ---------------------------------------------------------------------------
// In-place exclusive prefix over the chunk dimension.
// ---------------------------------------------------------------------------
__global__ __launch_bounds__(256) void prefix_chunks(
    float* __restrict__ Sc, float* __restrict__ Zc)
{
    const int STOT = BH_ * M_ * DH_;   // 272384
    const int ZTOT = BH_ * M_;         // 4256
    int idx = blockIdx.x * 256 + threadIdx.x;
    if (idx < STOT) {
        float run = 0.f;
        float* p = Sc + idx;
        #pragma unroll 1
        for (int c = 0; c < NCHUNK_; ++c) { float v = *p; *p = run; run += v; p += STOT; }
    } else if (idx < STOT + ZTOT) {
        float run = 0.f;
        float* p = Zc + (idx - STOT);
        #pragma unroll 1
        for (int c = 0; c < NCHUNK_; ++c) { float v = *p; *p = run; run += v; p += ZTOT; }
    }
}

// ---------------------------------------------------------------------------
// Per (chunk c, bh): ctx = (Q'@Sp + tril(Q'K'^T)@V) / (Q'@zp + rowsum(tril(Q'K'^T)))
// ---------------------------------------------------------------------------
__global__ __launch_bounds__(256) void chunk_attn(
    const float* __restrict__ Qh, const float* __restrict__ Kh,
    const float* __restrict__ Vh, const float* __restrict__ RF,
    const float* __restrict__ Sp, const float* __restrict__ Zp,
    float* __restrict__ ctx)
{
    __shared__ float sQt[64 * 64];   // phase1: Q^T [d][l]; phase2: masked A [i][j]
    __shared__ float sKt[64 * 64];   // phase1: K^T [d][l]; phase2: V [l][d]
    __shared__ float sqp[16 * 64];   // q' tile [mm][l]
    __shared__ float skp[16 * 64];   // k' tile [mm][l]
    __shared__ float sSp[16 * 64];   // S_prefix tile [mm][d]
    __shared__ float sRF[16 * 64];   // RF tile [mm][d]
    __shared__ float szp[16];
    __shared__ float shq[64], shk[64];
    const int c = blockIdx.x, bh = blockIdx.y;
    const int t = threadIdx.x;
    const int tm = t >> 4, tn = t & 15;
    const size_t chunkBase = ((size_t)bh * L_ + (size_t)c * CK_) * DH_;
    for (int u = t; u < 1024; u += 256) {
        float4 qv = *(const float4*)&Qh[chunkBase + (size_t)u * 4];
        float4 kv = *(const float4*)&Kh[chunkBase + (size_t)u * 4];
        int l = u >> 4, d0 = (u & 15) << 2;
        sQt[(d0+0)*64 + l] = qv.x; sQt[(d0+1)*64 + l] = qv.y;
        sQt[(d0+2)*64 + l] = qv.z; sQt[(d0+3)*64 + l] = qv.w;
        sKt[(d0+0)*64 + l] = kv.x; sKt[(d0+1)*64 + l] = kv.y;
        sKt[(d0+2)*64 + l] = kv.z; sKt[(d0+3)*64 + l] = kv.w;
    }
    __syncthreads();
    if (t < 64) {
        float s = 0.f;
        for (int d = 0; d < 64; ++d) { float v = sQt[d*64 + t]; s += v * v; }
        shq[t] = -0.5f * s;
    } else if (t < 128) {
        int l = t - 64;
        float s = 0.f;
        for (int d = 0; d < 64; ++d) { float v = sKt[d*64 + l]; s += v * v; }
        shk[l] = -0.5f * s;
    }
    float accA[4][4] = {};
    float accN[4][4] = {};
    float accD[4] = {};
    const size_t spBase = ((size_t)(c * BH_ + bh)) * M_ * DH_;
    const size_t zpBase = ((size_t)(c * BH_ + bh)) * M_;
    for (int mt = 0; mt < MT_; ++mt) {
        const int mbase = mt * 16;
        __syncthreads();
        {
            int mm = t >> 4, d0 = (t & 15) << 2;
            int m = mbase + mm;
            float4 rv = (m < M_) ? *(const float4*)&RF[(size_t)m * DH_ + d0]
                                 : make_float4(0.f, 0.f, 0.f, 0.f);
            *(float4*)&sRF[mm * 64 + d0] = rv;
            float4 sv = (m < M_) ? *(const float4*)&Sp[spBase + (size_t)m * DH_ + d0]
                                 : make_float4(0.f, 0.f, 0.f, 0.f);
            *(float4*)&sSp[mm * 64 + d0] = sv;
            if (t < 16) szp[t] = (mbase + t < M_) ? Zp[zpBase + mbase + t] : 0.f;
        }
        __syncthreads();
        {
            int l = t & 63, mg = t >> 6;
            float dq[4] = {}, dk[4] = {};
            for (int d = 0; d < 64; ++d) {
                float qv = sQt[d*64 + l], kv = sKt[d*64 + l];
                #pragma unroll
                for (int j = 0; j < 4; ++j) {
                    float r = sRF[(mg*4 + j)*64 + d];
                    dq[j] += r * qv;
                    dk[j] += r * kv;
                }
            }
            #pragma unroll
            for (int j = 0; j < 4; ++j) {
                int mm = mg*4 + j, m = mbase + mm;
                sqp[mm*64 + l] = (m < M_) ? __expf(shq[l] + dq[j]) : 0.f;
                skp[mm*64 + l] = (m < M_) ? __expf(shk[l] + dk[j]) : 0.f;
            }
        }
        __syncthreads();
        #pragma unroll 1
        for (int mm = 0; mm < 16; ++mm) {
            float4 q4 = *(const float4*)&sqp[mm*64 + (tm << 2)];
            float4 k4 = *(const float4*)&skp[mm*64 + (tn << 2)];
            float4 s4 = *(const float4*)&sSp[mm*64 + (tn << 2)];
            float zv = szp[mm];
            float qa[4] = {q4.x, q4.y, q4.z, q4.w};
            float ka[4] = {k4.x, k4.y, k4.z, k4.w};
            float sa[4] = {s4.x, s4.y, s4.z, s4.w};
            #pragma unroll
            for (int i = 0; i < 4; ++i) {
                #pragma unroll
                for (int j = 0; j < 4; ++j) {
                    accA[i][j] += qa[i] * ka[j];
                    accN[i][j] += qa[i] * sa[j];
                }
                accD[i] += qa[i] * zv;
            }
        }
    }
    __syncthreads();
    // phase 2: A (masked) -> sQt, V -> sKt
    for (int u = t; u < 1024; u += 256) {
        float4 vv = *(const float4*)&Vh[chunkBase + (size_t)u * 4];
        *(float4*)&sKt[u * 4] = vv;
    }
    #pragma unroll
    for (int i = 0; i < 4; ++i) {
        int gi = (tm << 2) + i;
        #pragma unroll
        for (int j = 0; j < 4; ++j) {
            int gj = (tn << 2) + j;
            sQt[gi*64 + gj] = (gi >= gj) ? accA[i][j] : 0.f;
        }
    }
    __syncthreads();
    float den2[4] = {};
    #pragma unroll 1
    for (int j = 0; j < 64; ++j) {
        float4 vv = *(const float4*)&sKt[j*64 + (tn << 2)];
        #pragma unroll
        for (int i = 0; i < 4; ++i) {
            float a = sQt[((tm << 2) + i)*64 + j];
            accN[i][0] += a * vv.x;
            accN[i][1] += a * vv.y;
            accN[i][2] += a * vv.z;
            accN[i][3] += a * vv.w;
            den2[i] += a;
        }
    }
    const int b = bh >> 3, h = bh & 7;
    #pragma unroll
    for (int i = 0; i < 4; ++i) {
        int l = c * CK_ + (tm << 2) + i;
        float invden = 1.f / (accD[i] + den2[i]);
        float4 o = make_float4(accN[i][0]*invden, accN[i][1]*invden,
                               accN[i][2]*invden, accN[i][3]*invden);
        *(float4*)&ctx[((size_t)(b * L_ + l)) * DM_ + h * DH_ + (tn << 2)] = o;
    }
}

extern "C" void kernel_launch(void* const* d_in, const int* in_sizes, int n_in,
                              void* d_out, int out_size, void* d_ws, size_t ws_size,
                              hipStream_t stream) {
    const float* query = (const float*)d_in[0];
    const float* key   = (const float*)d_in[1];
    const float* value = (const float*)d_in[2];
    const float* Wq    = (const float*)d_in[3];
    const float* bq    = (const float*)d_in[4];
    const float* Wk    = (const float*)d_in[5];
    const float* bk    = (const float*)d_in[6];
    const float* Wv    = (const float*)d_in[7];
    const float* bv    = (const float*)d_in[8];
    const float* Wout  = (const float*)d_in[9];
    const float* bout  = (const float*)d_in[10];
    const float* RF    = (const float*)d_in[11];
    float* out = (float*)d_out;

    float* ws  = (float*)d_ws;
    float* qh  = ws;                                   // BH*L*DH
    float* kh  = qh + (size_t)BH_ * L_ * DH_;
    float* vh  = kh + (size_t)BH_ * L_ * DH_;
    float* Sc  = vh + (size_t)BH_ * L_ * DH_;          // NCHUNK*BH*M*DH
    float* Zc  = Sc + (size_t)NCHUNK_ * BH_ * M_ * DH_;// NCHUNK*BH*M
    float* ctx = Zc + (size_t)NCHUNK_ * BH_ * M_;      // B*L*DM

    const float qscale = 0.21022410381342865f;  // 1 / 512^0.25

    dim3 gg(B_ * L_ / 64, DM_ / 64);
    gemm_xwt<<<gg, 256, 0, stream>>>(query, Wq, bq, qh, 1, qscale);
    gemm_xwt<<<gg, 256, 0, stream>>>(key,   Wk, bk, kh, 1, qscale);
    gemm_xwt<<<gg, 256, 0, stream>>>(value, Wv, bv, vh, 1, 1.0f);

    dim3 gc(NCHUNK_, BH_);
    chunk_sums<<<gc, 256, 0, stream>>>(kh, vh, RF, Sc, Zc);

    const int tot = BH_ * M_ * DH_ + BH_ * M_;
    prefix_chunks<<<(tot + 255) / 256, 256, 0, stream>>>(Sc, Zc);

    chunk_attn<<<gc, 256, 0, stream>>>(qh, kh, vh, RF, Sc, Zc, ctx);

    gemm_xwt<<<gg, 256, 0, stream>>>(ctx, Wout, bout, out, 0, 1.0f);
}

// Round 3
// 565.647 us; speedup vs baseline: 1.5536x; 1.5536x over previous
//
#include <hip/hip_runtime.h>
#include <hip/hip_bf16.h>

#define L_ 4096
#define MP 272            // M=266 padded to 272 (17x16)
#define BH16 16

typedef __attribute__((ext_vector_type(8))) __bf16 bf16x8;
typedef __attribute__((ext_vector_type(4))) float f32x4;

__device__ inline __bf16 f2b(float f) {
    unsigned u = __float_as_uint(f);
    unsigned r = (u + 0x7fffu + ((u >> 16) & 1u)) >> 16;
    unsigned short s = (unsigned short)r;
    return *reinterpret_cast<__bf16*>(&s);
}
__device__ inline float b2f(__bf16 b) {
    unsigned short s = *reinterpret_cast<unsigned short*>(&b);
    return __uint_as_float(((unsigned)s) << 16);
}

// ---------------------------------------------------------------------------
// prep: fp32->bf16 casts + RF pad + vT ones row
// ---------------------------------------------------------------------------
#define NX 4194304
#define NW 262144
__global__ __launch_bounds__(256) void prep(
    const float* __restrict__ q, const float* __restrict__ k, const float* __restrict__ v,
    const float* __restrict__ Wq, const float* __restrict__ Wk, const float* __restrict__ Wv,
    const float* __restrict__ Wout, const float* __restrict__ RF,
    __bf16* __restrict__ Xq, __bf16* __restrict__ Xk, __bf16* __restrict__ Xv,
    __bf16* __restrict__ Wqb, __bf16* __restrict__ Wkb, __bf16* __restrict__ Wvb,
    __bf16* __restrict__ Woutb, __bf16* __restrict__ RFb, __bf16* __restrict__ vT)
{
    long idx = (long)blockIdx.x * 256 + threadIdx.x;
    if (idx < NX) { Xq[idx] = f2b(q[idx]); return; }  idx -= NX;
    if (idx < NX) { Xk[idx] = f2b(k[idx]); return; }  idx -= NX;
    if (idx < NX) { Xv[idx] = f2b(v[idx]); return; }  idx -= NX;
    if (idx < NW) { Wqb[idx] = f2b(Wq[idx]); return; }  idx -= NW;
    if (idx < NW) { Wkb[idx] = f2b(Wk[idx]); return; }  idx -= NW;
    if (idx < NW) { Wvb[idx] = f2b(Wv[idx]); return; }  idx -= NW;
    if (idx < NW) { Woutb[idx] = f2b(Wout[idx]); return; }  idx -= NW;
    if (idx < MP * 64) { int row = (int)(idx >> 6); RFb[idx] = f2b(row < 266 ? RF[idx] : 0.f); return; }
    idx -= MP * 64;
    if (idx < 65536) {
        int bh = (int)(idx >> 12), l = (int)(idx & 4095);
        vT[((size_t)bh * 65 + 64) * L_ + l] = f2b(1.f);   // ones row (z / rowsum trick)
    }
}

// ---------------------------------------------------------------------------
// norms: hq/hk = -0.5*||row||^2 from bf16 qh/kh ([bh][l][64])
// ---------------------------------------------------------------------------
__global__ __launch_bounds__(256) void norms(
    const __bf16* __restrict__ qh, const __bf16* __restrict__ kh,
    float* __restrict__ hq, float* __restrict__ hk)
{
    int idx = blockIdx.x * 256 + threadIdx.x;     // 524288 = 131072 rows x 4
    int row = idx >> 2, qq = idx & 3;
    const __bf16* src = row < 65536 ? qh : kh;
    float* dst = row < 65536 ? hq : hk;
    int r = row & 65535;
    const uint4* p = (const uint4*)(src + (size_t)r * 64 + qq * 16);
    float s = 0.f;
    #pragma unroll
    for (int i = 0; i < 2; ++i) {
        uint4 u = p[i];
        unsigned arr[4] = {u.x, u.y, u.z, u.w};
        #pragma unroll
        for (int j = 0; j < 4; ++j) {
            float a = __uint_as_float(arr[j] << 16);
            float b = __uint_as_float(arr[j] & 0xffff0000u);
            s += a * a + b * b;
        }
    }
    s += __shfl_xor(s, 1);
    s += __shfl_xor(s, 2);
    if (qq == 0) dst[r] = -0.5f * s;
}

// ---------------------------------------------------------------------------
// Universal bf16 MFMA GEMM: C = A @ B^T (both operands K-contiguous rows),
// or B K-major (BKMAJ=1). 256 thr = 4 waves along M. Epilogue by EPI.
// batch decode: z = blockIdx.z, zb = z&15 (bh), zc = z>>4 (chunk)
// ---------------------------------------------------------------------------
template<int BM, int BN, int KSTEPS, int BKMAJ, int EPI>
__global__ __launch_bounds__(256) void gk(
    const __bf16* __restrict__ A, int lda, long sA1, long sA2, int Mreal,
    const __bf16* __restrict__ B, int ldb, long sB1, long sB2, int Nreal,
    int Kreal,
    void* __restrict__ O0p, long sO1, long sO2,
    float* __restrict__ O1p, long sP1, long sP2,
    const float* __restrict__ bias,
    const float* __restrict__ hrow, long sH1,
    float scale)
{
    static_assert(BM % 64 == 0 && BN % 16 == 0, "tile");
    constexpr int FM = BM / 64;
    constexpr int FN = BN / 16;
    __shared__ __bf16 Al[BM * 40];
    __shared__ __bf16 Bl[BKMAJ ? 32 * BN : BN * 40];
    const int t = threadIdx.x;
    const int w = t >> 6, lane = t & 63;
    const int z = blockIdx.z;
    const int zb = z & 15, zc = z >> 4;
    A += zb * sA1 + zc * sA2;
    B += zb * sB1 + zc * sB2;
    const int m0 = blockIdx.x * BM, n0 = blockIdx.y * BN;

    f32x4 acc[FM][FN];
    #pragma unroll
    for (int i = 0; i < FM; ++i)
        #pragma unroll
        for (int j = 0; j < FN; ++j)
            acc[i][j] = f32x4{0.f, 0.f, 0.f, 0.f};

    for (int ks = 0; ks < KSTEPS; ++ks) {
        const int kk = ks * 32;
        __syncthreads();
        // stage A [BM][32] -> LDS rows padded to 40
        for (int u = t; u < BM * 16; u += 256) {
            int r = u >> 4, dw = u & 15;
            int gr = m0 + r, g2 = kk + dw * 2;
            unsigned v = 0;
            if (gr < Mreal && g2 < Kreal)
                v = *(const unsigned*)(A + (size_t)gr * lda + g2);
            *(unsigned*)&Al[r * 40 + dw * 2] = v;
        }
        if constexpr (!BKMAJ) {
            for (int u = t; u < BN * 16; u += 256) {
                int r = u >> 4, dw = u & 15;
                int gn = n0 + r, g2 = kk + dw * 2;
                unsigned v = 0;
                if (gn < Nreal && g2 < Kreal)
                    v = *(const unsigned*)(B + (size_t)gn * ldb + g2);
                *(unsigned*)&Bl[r * 40 + dw * 2] = v;
            }
        } else {
            // B [32 k][BN n] K-major with per-8-row rotation swizzle (BN must be 64)
            for (int u = t; u < 32 * (BN / 2); u += 256) {
                int r = u / (BN / 2), dw = u % (BN / 2);
                int gkr = kk + r;
                unsigned v = 0;
                if (gkr < Kreal)
                    v = *(const unsigned*)(B + (size_t)gkr * ldb + n0 + dw * 2);
                int col = (dw * 2 + ((r >> 3) << 4)) & 63;
                *(unsigned*)&Bl[r * BN + col] = v;
            }
        }
        __syncthreads();
        bf16x8 af[FM], bfr[FN];
        #pragma unroll
        for (int i = 0; i < FM; ++i) {
            int row = w * (BM / 4) + i * 16 + (lane & 15);
            af[i] = *(const bf16x8*)&Al[row * 40 + (lane >> 4) * 8];
        }
        #pragma unroll
        for (int j = 0; j < FN; ++j) {
            if constexpr (!BKMAJ) {
                int nr = j * 16 + (lane & 15);
                bfr[j] = *(const bf16x8*)&Bl[nr * 40 + (lane >> 4) * 8];
            } else {
                int n = j * 16 + (lane & 15);
                int kc = (lane >> 4) * 8;
                int ncol = (n + ((kc >> 3) << 4)) & 63;
                bf16x8 tmp;
                #pragma unroll
                for (int e = 0; e < 8; ++e) tmp[e] = Bl[(kc + e) * BN + ncol];
                bfr[j] = tmp;
            }
        }
        #pragma unroll
        for (int i = 0; i < FM; ++i)
            #pragma unroll
            for (int j = 0; j < FN; ++j)
                acc[i][j] = __builtin_amdgcn_mfma_f32_16x16x32_bf16(af[i], bfr[j], acc[i][j], 0, 0, 0);
    }

    // epilogue: r = global row (M), cn = global col (N)
    const int rb = m0 + w * (BM / 4);
    #pragma unroll
    for (int i = 0; i < FM; ++i) {
        #pragma unroll
        for (int j = 0; j < FN; ++j) {
            #pragma unroll
            for (int e = 0; e < 4; ++e) {
                int r = rb + i * 16 + ((lane >> 4) << 2) + e;
                int cn = n0 + j * 16 + (lane & 15);
                float val = acc[i][j][e];
                if constexpr (EPI == 0) {          // proj q/k -> qh/kh [bh][l][64]
                    float v = (val + bias[cn]) * scale;
                    int b = r >> 12, l = r & 4095, h = cn >> 6, d = cn & 63;
                    ((__bf16*)O0p)[(((size_t)(b * 8 + h) * L_ + l) << 6) + d] = f2b(v);
                } else if constexpr (EPI == 1) {   // proj v -> vT [bh][65][4096]
                    float v = val + bias[cn];
                    int b = r >> 12, l = r & 4095, h = cn >> 6, d = cn & 63;
                    ((__bf16*)O0p)[((size_t)(b * 8 + h) * 65 + d) * L_ + l] = f2b(v);
                } else if constexpr (EPI == 2) {   // out fp32 [8192][512]
                    ((float*)O0p)[(size_t)r * 512 + cn] = val + bias[cn];
                } else if constexpr (EPI == 3) {   // q' = exp(h+val) [bh][l][MP]
                    float v = (cn < 266) ? __expf(hrow[zb * sH1 + r] + val) : 0.f;
                    ((__bf16*)O0p + zb * sO1)[(size_t)r * MP + cn] = f2b(v);
                } else if constexpr (EPI == 4) {   // k'T = exp(h+val) [bh][MP][4096]
                    float v = (cn < 266) ? __expf(hrow[zb * sH1 + r] + val) : 0.f;
                    ((__bf16*)O0p + zb * sO1)[(size_t)cn * L_ + r] = f2b(v);
                } else if constexpr (EPI == 5) {   // ScT transposed store [65][MP]
                    if (r < MP && cn < 65)
                        ((__bf16*)O0p + zb * sO1 + zc * sO2)[(size_t)cn * MP + r] = f2b(val);
                } else if constexpr (EPI == 6) {   // P1 fp32 + den col
                    float* P = (float*)O0p + zb * sO1 + zc * sO2;
                    if (cn < 64) P[r * 64 + cn] = val;
                    else if (cn == 64) (O1p + zb * sP1 + zc * sP2)[r] = val;
                } else if constexpr (EPI == 7) {   // tril mask, bf16
                    ((__bf16*)O0p + zb * sO1 + zc * sO2)[r * 64 + cn] = f2b(r >= cn ? val : 0.f);
                } else if constexpr (EPI == 8) {   // accumulate into P1/den
                    float* P = (float*)O0p + zb * sO1 + zc * sO2;
                    if (cn < 64) P[r * 64 + cn] += val;
                    else if (cn == 64) (O1p + zb * sP1 + zc * sP2)[r] += val;
                }
            }
        }
    }
}

// ---------------------------------------------------------------------------
// exclusive prefix over chunks, in place on bf16 ScT (fp32 accumulator)
// ---------------------------------------------------------------------------
__global__ __launch_bounds__(256) void prefixk(__bf16* __restrict__ ScT)
{
    int idx = blockIdx.x * 256 + threadIdx.x;
    const int STRIDE = BH16 * 65 * MP;   // 282880
    if (idx >= STRIDE) return;
    __bf16* p = ScT + idx;
    float run = 0.f;
    #pragma unroll 1
    for (int c = 0; c < 64; ++c) {
        float v = b2f(*p);
        *p = f2b(run);
        run += v;
        p += STRIDE;
    }
}

// ---------------------------------------------------------------------------
// combine: ctx[b, c*64+l, h*64+d] = P1 / den   (bf16 out)
// ---------------------------------------------------------------------------
__global__ __launch_bounds__(256) void combinek(
    const float* __restrict__ P1, const float* __restrict__ den, __bf16* __restrict__ ctx)
{
    int z = blockIdx.x;
    int bh = z & 15, c = z >> 4;
    int t = threadIdx.x;
    int l = t >> 2, dq = t & 3;
    const float* P = P1 + (size_t)z * 4096 + l * 64 + dq * 16;
    float inv = 1.f / den[(size_t)z * 64 + l];
    int b = bh >> 3, h = bh & 7;
    __bf16* o = ctx + ((size_t)(b * L_ + (c << 6) + l)) * 512 + (h << 6) + dq * 16;
    #pragma unroll
    for (int i = 0; i < 16; ++i) o[i] = f2b(P[i] * inv);
}

extern "C" void kernel_launch(void* const* d_in, const int* in_sizes, int n_in,
                              void* d_out, int out_size, void* d_ws, size_t ws_size,
                              hipStream_t stream) {
    const float* query = (const float*)d_in[0];
    const float* key   = (const float*)d_in[1];
    const float* value = (const float*)d_in[2];
    const float* Wq    = (const float*)d_in[3];
    const float* bq    = (const float*)d_in[4];
    const float* Wk    = (const float*)d_in[5];
    const float* bk    = (const float*)d_in[6];
    const float* Wv    = (const float*)d_in[7];
    const float* bv    = (const float*)d_in[8];
    const float* Wout  = (const float*)d_in[9];
    const float* bout  = (const float*)d_in[10];
    const float* RF    = (const float*)d_in[11];

    char* w8 = (char*)d_ws;
    // arena (overlaid lifetimes; total 134,154,240 B < 137.9 MB proven budget)
    __bf16* q_p  = (__bf16*)(w8 + 0);              // q' [16][4096][272]  (late)
    __bf16* Xq   = (__bf16*)(w8 + 0);              // early casts live under q'
    __bf16* Xk   = (__bf16*)(w8 + 8388608);
    __bf16* Xv   = (__bf16*)(w8 + 16777216);
    __bf16* Wqb  = (__bf16*)(w8 + 25165824);
    __bf16* Wkb  = (__bf16*)(w8 + 25690112);
    __bf16* Wvb  = (__bf16*)(w8 + 26214400);
    __bf16* ctx  = (__bf16*)(w8 + 0);              // after A-chunk GEMM, over q'
    __bf16* kT   = (__bf16*)(w8 + 35651584);       // k'T [16][272][4096]
    __bf16* ScT  = (__bf16*)(w8 + 71303168);       // [64][16][65][272]
    __bf16* Atr  = (__bf16*)(w8 + 71303168);       // after P1 GEMM, over ScT
    __bf16* vT   = (__bf16*)(w8 + 107511808);      // [16][65][4096]
    __bf16* qh   = (__bf16*)(w8 + 116031488);      // [16][4096][64]
    __bf16* kh   = (__bf16*)(w8 + 124420096);
    float*  P1   = (float*) (w8 + 116031488);      // after rf-proj, over qh/kh
    __bf16* Woutb= (__bf16*)(w8 + 132808704);
    float*  hq   = (float*) (w8 + 133332992);
    float*  hk   = (float*) (w8 + 133595136);
    __bf16* RFb  = (__bf16*)(w8 + 133857280);
    float*  den  = (float*) (w8 + 133892096);

    const float qscale = 0.21022410381342865f;     // 512^-0.25

    prep<<<53573, 256, 0, stream>>>(query, key, value, Wq, Wk, Wv, Wout, RF,
                                    Xq, Xk, Xv, Wqb, Wkb, Wvb, Woutb, RFb, vT);

    // projections: C = X @ W^T (+bias)*scale
    gk<128,64,16,0,0><<<dim3(64,8,1),256,0,stream>>>(Xq,512,0,0,8192, Wqb,512,0,0,512, 512,
        qh,0,0, nullptr,0,0, bq, nullptr,0, qscale);
    gk<128,64,16,0,0><<<dim3(64,8,1),256,0,stream>>>(Xk,512,0,0,8192, Wkb,512,0,0,512, 512,
        kh,0,0, nullptr,0,0, bk, nullptr,0, qscale);
    gk<128,64,16,0,1><<<dim3(64,8,1),256,0,stream>>>(Xv,512,0,0,8192, Wvb,512,0,0,512, 512,
        vT,0,0, nullptr,0,0, bv, nullptr,0, 1.f);

    norms<<<2048, 256, 0, stream>>>(qh, kh, hq, hk);

    // RF projection + exp:  q' natural, k' transposed
    gk<64,16,2,0,3><<<dim3(64,17,16),256,0,stream>>>(qh,64,262144,0,4096, RFb,64,0,0,MP, 64,
        q_p,1114112,0, nullptr,0,0, nullptr, hq,4096, 0.f);
    gk<64,16,2,0,4><<<dim3(64,17,16),256,0,stream>>>(kh,64,262144,0,4096, RFb,64,0,0,MP, 64,
        kT,1114112,0, nullptr,0,0, nullptr, hk,4096, 0.f);

    // chunk sums: ScT[d][m] = sum_l vT[d][l] k'T[m][l]  (d=64 row is z via ones row)
    gk<64,80,2,0,5><<<dim3(5,1,1024),256,0,stream>>>(kT,4096,1114112,64,MP, vT,4096,266240,64,65, 64,
        ScT,17680,282880, nullptr,0,0, nullptr, nullptr,0, 0.f);

    prefixk<<<1105, 256, 0, stream>>>(ScT);

    // P1 = q'chunk @ Sp (num prefix part; col 64 -> den)
    gk<64,80,9,0,6><<<dim3(1,1,1024),256,0,stream>>>(q_p,MP,1114112,17408,64, ScT,MP,17680,282880,65, MP,
        P1,4096,65536, den,64,1024, nullptr, nullptr,0, 0.f);

    // A = tril(q'chunk @ k'chunk^T)  (B K-major path)
    gk<64,64,9,1,7><<<dim3(1,1,1024),256,0,stream>>>(q_p,MP,1114112,17408,64, kT,4096,1114112,64,64, MP,
        Atr,4096,65536, nullptr,0,0, nullptr, nullptr,0, 0.f);

    // P1 += A @ V (ones row adds rowsum(A) to den)
    gk<64,80,2,0,8><<<dim3(1,1,1024),256,0,stream>>>(Atr,64,4096,65536,64, vT,4096,266240,64,65, 64,
        P1,4096,65536, den,64,1024, nullptr, nullptr,0, 0.f);

    combinek<<<1024, 256, 0, stream>>>(P1, den, ctx);

    // out = ctx @ Wout^T + bout  (fp32)
    gk<128,64,16,0,2><<<dim3(64,8,1),256,0,stream>>>(ctx,512,0,0,8192, Woutb,512,0,0,512, 512,
        d_out,0,0, nullptr,0,0, bout, nullptr,0, 1.f);
}

// Round 4
// 337.298 us; speedup vs baseline: 2.6053x; 1.6770x over previous
//
#include <hip/hip_runtime.h>
#include <hip/hip_bf16.h>

#define L_ 4096
#define MP 272            // M=266 padded to 272
#define BH16 16

typedef __attribute__((ext_vector_type(8))) __bf16 bf16x8;
typedef __attribute__((ext_vector_type(4))) float f32x4;

__device__ inline __bf16 f2b(float f) {
    unsigned u = __float_as_uint(f);
    unsigned r = (u + 0x7fffu + ((u >> 16) & 1u)) >> 16;
    unsigned short s = (unsigned short)r;
    return *reinterpret_cast<__bf16*>(&s);
}
__device__ inline float b2f(__bf16 b) {
    unsigned short s = *reinterpret_cast<unsigned short*>(&b);
    return __uint_as_float(((unsigned)s) << 16);
}

// ---------------------------------------------------------------------------
// prep2: weight casts + RF pad + vT ones row (activations are cast in-GEMM)
// ---------------------------------------------------------------------------
#define NW 262144
__global__ __launch_bounds__(256) void prep2(
    const float* __restrict__ Wq, const float* __restrict__ Wk, const float* __restrict__ Wv,
    const float* __restrict__ Wout, const float* __restrict__ RF,
    __bf16* __restrict__ Wqb, __bf16* __restrict__ Wkb, __bf16* __restrict__ Wvb,
    __bf16* __restrict__ Woutb, __bf16* __restrict__ RFb, __bf16* __restrict__ vT)
{
    long idx = (long)blockIdx.x * 256 + threadIdx.x;
    if (idx < NW) { Wqb[idx] = f2b(Wq[idx]); return; }  idx -= NW;
    if (idx < NW) { Wkb[idx] = f2b(Wk[idx]); return; }  idx -= NW;
    if (idx < NW) { Wvb[idx] = f2b(Wv[idx]); return; }  idx -= NW;
    if (idx < NW) { Woutb[idx] = f2b(Wout[idx]); return; }  idx -= NW;
    if (idx < MP * 64) { int row = (int)(idx >> 6); RFb[idx] = f2b(row < 266 ? RF[idx] : 0.f); return; }
    idx -= MP * 64;
    if (idx < 65536) {
        int bh = (int)(idx >> 12), l = (int)(idx & 4095);
        vT[((size_t)bh * 65 + 64) * L_ + l] = f2b(1.f);   // ones row (den trick)
    }
}

// ---------------------------------------------------------------------------
// norms: hq/hk = -0.5*||row||^2 from bf16 qh/kh ([bh][l][64])
// ---------------------------------------------------------------------------
__global__ __launch_bounds__(256) void norms(
    const __bf16* __restrict__ qh, const __bf16* __restrict__ kh,
    float* __restrict__ hq, float* __restrict__ hk)
{
    int idx = blockIdx.x * 256 + threadIdx.x;
    int row = idx >> 2, qq = idx & 3;
    const __bf16* src = row < 65536 ? qh : kh;
    float* dst = row < 65536 ? hq : hk;
    int r = row & 65535;
    const uint4* p = (const uint4*)(src + (size_t)r * 64 + qq * 16);
    float s = 0.f;
    #pragma unroll
    for (int i = 0; i < 2; ++i) {
        uint4 u = p[i];
        unsigned arr[4] = {u.x, u.y, u.z, u.w};
        #pragma unroll
        for (int j = 0; j < 4; ++j) {
            float a = __uint_as_float(arr[j] << 16);
            float b = __uint_as_float(arr[j] & 0xffff0000u);
            s += a * a + b * b;
        }
    }
    s += __shfl_xor(s, 1);
    s += __shfl_xor(s, 2);
    if (qq == 0) dst[r] = -0.5f * s;
}

// ---------------------------------------------------------------------------
// proj: C = A @ W^T + bias. A fp32 (AF32=1, cvt in staging) or bf16.
// 128x64 tile, K=512. EPI 0: qh/kh [bh][l][64]; 1: vT via LDS transpose;
// 2: fp32 out.
// ---------------------------------------------------------------------------
template<int AF32, int EPI>
__global__ __launch_bounds__(256) void proj(
    const void* __restrict__ Ap, const __bf16* __restrict__ W,
    const float* __restrict__ bias, void* __restrict__ O,
    float scale)
{
    __shared__ __bf16 Al[128 * 40];
    __shared__ __bf16 Bl[64 * 40];
    const int t = threadIdx.x;
    const int w = t >> 6, lane = t & 63;
    const int m0 = blockIdx.x * 128, n0 = blockIdx.y * 64;

    f32x4 acc[2][4];
    #pragma unroll
    for (int i = 0; i < 2; ++i)
        #pragma unroll
        for (int j = 0; j < 4; ++j) acc[i][j] = f32x4{0.f,0.f,0.f,0.f};

    for (int ks = 0; ks < 16; ++ks) {
        const int kk = ks * 32;
        __syncthreads();
        if constexpr (AF32) {
            const float* A = (const float*)Ap;
            #pragma unroll
            for (int it = 0; it < 4; ++it) {
                int u = t + it * 256;
                int r = u >> 3, qd = (u & 7) << 2;
                float4 v = *(const float4*)&A[(size_t)(m0 + r) * 512 + kk + qd];
                __bf16* dst = &Al[r * 40 + qd];
                dst[0] = f2b(v.x); dst[1] = f2b(v.y); dst[2] = f2b(v.z); dst[3] = f2b(v.w);
            }
        } else {
            const __bf16* A = (const __bf16*)Ap;
            #pragma unroll
            for (int it = 0; it < 8; ++it) {
                int u = t + it * 256;
                int r = u >> 4, dw = (u & 15) << 1;
                *(unsigned*)&Al[r * 40 + dw] = *(const unsigned*)&A[(size_t)(m0 + r) * 512 + kk + dw];
            }
        }
        #pragma unroll
        for (int it = 0; it < 4; ++it) {
            int u = t + it * 256;
            int r = u >> 4, dw = (u & 15) << 1;
            *(unsigned*)&Bl[r * 40 + dw] = *(const unsigned*)&W[(size_t)(n0 + r) * 512 + kk + dw];
        }
        __syncthreads();
        bf16x8 af[2], bfr[4];
        #pragma unroll
        for (int i = 0; i < 2; ++i)
            af[i] = *(const bf16x8*)&Al[(w * 32 + i * 16 + (lane & 15)) * 40 + (lane >> 4) * 8];
        #pragma unroll
        for (int j = 0; j < 4; ++j)
            bfr[j] = *(const bf16x8*)&Bl[(j * 16 + (lane & 15)) * 40 + (lane >> 4) * 8];
        #pragma unroll
        for (int i = 0; i < 2; ++i)
            #pragma unroll
            for (int j = 0; j < 4; ++j)
                acc[i][j] = __builtin_amdgcn_mfma_f32_16x16x32_bf16(af[i], bfr[j], acc[i][j], 0, 0, 0);
    }

    if constexpr (EPI == 1) {
        __shared__ __bf16 Tv[64 * 136];
        #pragma unroll
        for (int i = 0; i < 2; ++i)
            #pragma unroll
            for (int j = 0; j < 4; ++j)
                #pragma unroll
                for (int e = 0; e < 4; ++e) {
                    int rl = w * 32 + i * 16 + ((lane >> 4) << 2) + e;
                    int cn = n0 + j * 16 + (lane & 15);
                    Tv[(cn & 63) * 136 + rl] = f2b(acc[i][j][e] + bias[cn]);
                }
        __syncthreads();
        __bf16* vT = (__bf16*)O;
        int b = m0 >> 12, l0 = m0 & 4095, h = n0 >> 6;
        #pragma unroll
        for (int it = 0; it < 4; ++it) {
            int v = t + it * 256;
            int d = v >> 4, seg = v & 15;
            *(uint4*)&vT[((size_t)(b * 8 + h) * 65 + d) * L_ + l0 + seg * 8] =
                *(const uint4*)&Tv[d * 136 + seg * 8];
        }
    } else {
        #pragma unroll
        for (int i = 0; i < 2; ++i)
            #pragma unroll
            for (int j = 0; j < 4; ++j)
                #pragma unroll
                for (int e = 0; e < 4; ++e) {
                    int r = m0 + w * 32 + i * 16 + ((lane >> 4) << 2) + e;
                    int cn = n0 + j * 16 + (lane & 15);
                    float val = acc[i][j][e];
                    if constexpr (EPI == 0) {
                        float vv = (val + bias[cn]) * scale;
                        int b = r >> 12, l = r & 4095, h = cn >> 6, d = cn & 63;
                        ((__bf16*)O)[(((size_t)(b * 8 + h) * L_ + l) << 6) + d] = f2b(vv);
                    } else {
                        ((float*)O)[(size_t)r * 512 + cn] = val + bias[cn];
                    }
                }
    }
}

// ---------------------------------------------------------------------------
// rfproj: per (l-block, bh): 64x272 tile, K=64.  val -> exp(h + val).
// QK=0: write q' natural [bh][l][MP].  QK=1: write k'T [bh][m][L] via LDS T.
// ---------------------------------------------------------------------------
template<int QK>
__global__ __launch_bounds__(256) void rfproj(
    const __bf16* __restrict__ X, const __bf16* __restrict__ RFb,
    const float* __restrict__ hrow, __bf16* __restrict__ O)
{
    __shared__ __bf16 Al[64 * 40];
    __shared__ __bf16 Bl[MP * 40];
    const int t = threadIdx.x;
    const int w = t >> 6, lane = t & 63;
    const int l0 = blockIdx.x * 64, bh = blockIdx.y;
    const __bf16* A = X + (size_t)bh * 262144;

    f32x4 acc[17];
    #pragma unroll
    for (int j = 0; j < 17; ++j) acc[j] = f32x4{0.f,0.f,0.f,0.f};

    for (int ks = 0; ks < 2; ++ks) {
        const int kk = ks * 32;
        __syncthreads();
        #pragma unroll
        for (int it = 0; it < 4; ++it) {
            int u = t + it * 256;
            int r = u >> 4, dw = (u & 15) << 1;
            *(unsigned*)&Al[r * 40 + dw] = *(const unsigned*)&A[(size_t)(l0 + r) * 64 + kk + dw];
        }
        #pragma unroll
        for (int it = 0; it < 17; ++it) {
            int u = t + it * 256;
            int r = u >> 4, dw = (u & 15) << 1;
            *(unsigned*)&Bl[r * 40 + dw] = *(const unsigned*)&RFb[(size_t)r * 64 + kk + dw];
        }
        __syncthreads();
        bf16x8 af = *(const bf16x8*)&Al[(w * 16 + (lane & 15)) * 40 + (lane >> 4) * 8];
        #pragma unroll
        for (int j = 0; j < 17; ++j) {
            bf16x8 bfr = *(const bf16x8*)&Bl[(j * 16 + (lane & 15)) * 40 + (lane >> 4) * 8];
            acc[j] = __builtin_amdgcn_mfma_f32_16x16x32_bf16(af, bfr, acc[j], 0, 0, 0);
        }
    }

    if constexpr (QK == 0) {
        #pragma unroll
        for (int j = 0; j < 17; ++j)
            #pragma unroll
            for (int e = 0; e < 4; ++e) {
                int rl = w * 16 + ((lane >> 4) << 2) + e;
                int cn = j * 16 + (lane & 15);
                float h = hrow[bh * 4096 + l0 + rl];
                float v = (cn < 266) ? __expf(h + acc[j][e]) : 0.f;
                O[(size_t)bh * 1114112 + (size_t)(l0 + rl) * MP + cn] = f2b(v);
            }
    } else {
        __shared__ __bf16 T[MP * 72];
        #pragma unroll
        for (int j = 0; j < 17; ++j)
            #pragma unroll
            for (int e = 0; e < 4; ++e) {
                int rl = w * 16 + ((lane >> 4) << 2) + e;
                int cn = j * 16 + (lane & 15);
                float h = hrow[bh * 4096 + l0 + rl];
                float v = (cn < 266) ? __expf(h + acc[j][e]) : 0.f;
                T[cn * 72 + rl] = f2b(v);
            }
        __syncthreads();
        for (int v = t; v < MP * 8; v += 256) {
            int m = v >> 3, seg = v & 7;
            *(uint4*)&O[(size_t)bh * 1114112 + (size_t)m * L_ + l0 + seg * 8] =
                *(const uint4*)&T[m * 72 + seg * 8];
        }
    }
}

// ---------------------------------------------------------------------------
// chunk_sums2: ScT[c][bh][d][m] = sum_l v[l][d] k'[l][m]  (d=64 row is z)
// A = kT rows m, B = vT rows d, K=64.  Output via LDS transpose.
// ---------------------------------------------------------------------------
__global__ __launch_bounds__(256) void chunk_sums2(
    const __bf16* __restrict__ kT, const __bf16* __restrict__ vT,
    __bf16* __restrict__ ScT)
{
    __shared__ __bf16 Al[64 * 40];
    __shared__ __bf16 Bl[80 * 40];
    __shared__ __bf16 T2[80 * 72];
    const int t = threadIdx.x;
    const int w = t >> 6, lane = t & 63;
    const int m0 = blockIdx.x * 64;
    const int z = blockIdx.z, zb = z & 15, zc = z >> 4;
    const __bf16* A = kT + (size_t)zb * 1114112 + zc * 64;
    const __bf16* B = vT + (size_t)zb * 266240 + zc * 64;

    f32x4 acc[5];
    #pragma unroll
    for (int j = 0; j < 5; ++j) acc[j] = f32x4{0.f,0.f,0.f,0.f};

    for (int ks = 0; ks < 2; ++ks) {
        const int kk = ks * 32;
        __syncthreads();
        #pragma unroll
        for (int it = 0; it < 4; ++it) {
            int u = t + it * 256;
            int r = u >> 4, dw = (u & 15) << 1;
            unsigned v = 0;
            if (m0 + r < MP) v = *(const unsigned*)&A[(size_t)(m0 + r) * L_ + kk + dw];
            *(unsigned*)&Al[r * 40 + dw] = v;
        }
        #pragma unroll
        for (int it = 0; it < 5; ++it) {
            int u = t + it * 256;
            int r = u >> 4, dw = (u & 15) << 1;
            unsigned v = 0;
            if (r < 65) v = *(const unsigned*)&B[(size_t)r * L_ + kk + dw];
            *(unsigned*)&Bl[r * 40 + dw] = v;
        }
        __syncthreads();
        bf16x8 af = *(const bf16x8*)&Al[(w * 16 + (lane & 15)) * 40 + (lane >> 4) * 8];
        #pragma unroll
        for (int j = 0; j < 5; ++j) {
            bf16x8 bfr = *(const bf16x8*)&Bl[(j * 16 + (lane & 15)) * 40 + (lane >> 4) * 8];
            acc[j] = __builtin_amdgcn_mfma_f32_16x16x32_bf16(af, bfr, acc[j], 0, 0, 0);
        }
    }
    #pragma unroll
    for (int j = 0; j < 5; ++j)
        #pragma unroll
        for (int e = 0; e < 4; ++e) {
            int rl = w * 16 + ((lane >> 4) << 2) + e;
            int cn = j * 16 + (lane & 15);
            T2[cn * 72 + rl] = f2b(acc[j][e]);
        }
    __syncthreads();
    __bf16* Obase = ScT + (size_t)(zc * 16 + zb) * 17680;
    for (int v = t; v < 65 * 8; v += 256) {
        int row = v >> 3, seg = v & 7;
        int m = m0 + seg * 8;
        if (m < MP)
            *(uint4*)&Obase[(size_t)row * MP + m] = *(const uint4*)&T2[row * 72 + seg * 8];
    }
}

// ---------------------------------------------------------------------------
// exclusive prefix over chunks, in place on bf16 ScT (fp32 accumulator)
// ---------------------------------------------------------------------------
__global__ __launch_bounds__(256) void prefixk(__bf16* __restrict__ ScT)
{
    int idx = blockIdx.x * 256 + threadIdx.x;
    const int STRIDE = BH16 * 65 * MP;   // 282880
    if (idx >= STRIDE) return;
    __bf16* p = ScT + idx;
    float run = 0.f;
    #pragma unroll 1
    for (int c = 0; c < 64; ++c) {
        float v = b2f(*p);
        *p = f2b(run);
        run += v;
        p += STRIDE;
    }
}

// ---------------------------------------------------------------------------
// fusedD: per (c,bh): S=tril(q'k'^T); acc2 = q'@Sp^T + S@Vext; ctx = num/den
// ---------------------------------------------------------------------------
__global__ __launch_bounds__(256) void fusedD(
    const __bf16* __restrict__ q_p, const __bf16* __restrict__ kT,
    const __bf16* __restrict__ ScT, const __bf16* __restrict__ vT,
    __bf16* __restrict__ ctx)
{
    __shared__ __bf16 Aq[64 * 40];
    __shared__ __bf16 B1[64 * 40];
    __shared__ __bf16 B2[80 * 40];
    __shared__ __bf16 Sl[64 * 72];
    __shared__ float sden[64];
    const int t = threadIdx.x;
    const int w = t >> 6, lane = t & 63;
    const int z = blockIdx.x, zb = z & 15, zc = z >> 4;
    const __bf16* qp_b = q_p + (size_t)zb * 1114112 + (size_t)(zc * 64) * MP;
    const __bf16* kT_b = kT + (size_t)zb * 1114112 + zc * 64;
    const __bf16* Sp_b = ScT + (size_t)(zc * 16 + zb) * 17680;
    const __bf16* vT_b = vT + (size_t)zb * 266240 + zc * 64;

    f32x4 acc1[4], acc2[5];
    #pragma unroll
    for (int j = 0; j < 4; ++j) acc1[j] = f32x4{0.f,0.f,0.f,0.f};
    #pragma unroll
    for (int j = 0; j < 5; ++j) acc2[j] = f32x4{0.f,0.f,0.f,0.f};

    for (int ks = 0; ks < 9; ++ks) {
        const int kk = ks * 32;
        __syncthreads();
        // A = q' rows l, K=m
        #pragma unroll
        for (int it = 0; it < 4; ++it) {
            int u = t + it * 256;
            int r = u >> 4, dw = (u & 15) << 1;
            unsigned v = 0;
            if (kk + dw < MP) v = *(const unsigned*)&qp_b[(size_t)r * MP + kk + dw];
            *(unsigned*)&Aq[r * 40 + dw] = v;
        }
        // B1 = k' rows l' over m  (transposed staging from kT[m][l])
        {
            int mrow = kk + (t >> 3), seg = t & 7;
            if (mrow < MP) {
                uint4 vv = *(const uint4*)&kT_b[(size_t)mrow * L_ + seg * 8];
                const __bf16* pv = (const __bf16*)&vv;
                #pragma unroll
                for (int e = 0; e < 8; ++e)
                    B1[(seg * 8 + e) * 40 + (mrow - kk)] = pv[e];
            } else {
                #pragma unroll
                for (int e = 0; e < 8; ++e) {
                    unsigned short zz = 0;
                    B1[(seg * 8 + e) * 40 + (mrow - kk)] = *reinterpret_cast<__bf16*>(&zz);
                }
            }
        }
        // B2 = Sp rows d, K=m
        #pragma unroll
        for (int it = 0; it < 5; ++it) {
            int u = t + it * 256;
            int r = u >> 4, dw = (u & 15) << 1;
            unsigned v = 0;
            if (r < 65 && kk + dw < MP) v = *(const unsigned*)&Sp_b[(size_t)r * MP + kk + dw];
            *(unsigned*)&B2[r * 40 + dw] = v;
        }
        __syncthreads();
        bf16x8 af = *(const bf16x8*)&Aq[(w * 16 + (lane & 15)) * 40 + (lane >> 4) * 8];
        #pragma unroll
        for (int j = 0; j < 4; ++j) {
            bf16x8 bfr = *(const bf16x8*)&B1[(j * 16 + (lane & 15)) * 40 + (lane >> 4) * 8];
            acc1[j] = __builtin_amdgcn_mfma_f32_16x16x32_bf16(af, bfr, acc1[j], 0, 0, 0);
        }
        #pragma unroll
        for (int j = 0; j < 5; ++j) {
            bf16x8 bfr = *(const bf16x8*)&B2[(j * 16 + (lane & 15)) * 40 + (lane >> 4) * 8];
            acc2[j] = __builtin_amdgcn_mfma_f32_16x16x32_bf16(af, bfr, acc2[j], 0, 0, 0);
        }
    }
    __syncthreads();
    // tril mask -> Sl (bf16, A-operand layout [l][l'] pad 72)
    #pragma unroll
    for (int j = 0; j < 4; ++j)
        #pragma unroll
        for (int e = 0; e < 4; ++e) {
            int rl = w * 16 + ((lane >> 4) << 2) + e;
            int cn = j * 16 + (lane & 15);
            Sl[rl * 72 + cn] = f2b(rl >= cn ? acc1[j][e] : 0.f);
        }
    __syncthreads();
    // phase 3: acc2 += S @ Vext
    for (int ks = 0; ks < 2; ++ks) {
        const int kk = ks * 32;
        __syncthreads();
        #pragma unroll
        for (int it = 0; it < 5; ++it) {
            int u = t + it * 256;
            int r = u >> 4, dw = (u & 15) << 1;
            unsigned v = 0;
            if (r < 65) v = *(const unsigned*)&vT_b[(size_t)r * L_ + kk + dw];
            *(unsigned*)&B2[r * 40 + dw] = v;
        }
        __syncthreads();
        bf16x8 as = *(const bf16x8*)&Sl[(w * 16 + (lane & 15)) * 72 + kk + (lane >> 4) * 8];
        #pragma unroll
        for (int j = 0; j < 5; ++j) {
            bf16x8 bfr = *(const bf16x8*)&B2[(j * 16 + (lane & 15)) * 40 + (lane >> 4) * 8];
            acc2[j] = __builtin_amdgcn_mfma_f32_16x16x32_bf16(as, bfr, acc2[j], 0, 0, 0);
        }
    }
    // den broadcast
    if ((lane & 15) == 0) {
        #pragma unroll
        for (int e = 0; e < 4; ++e)
            sden[w * 16 + ((lane >> 4) << 2) + e] = acc2[4][e];
    }
    __syncthreads();
    const int b = zb >> 3, h = zb & 7;
    #pragma unroll
    for (int j = 0; j < 4; ++j)
        #pragma unroll
        for (int e = 0; e < 4; ++e) {
            int rl = w * 16 + ((lane >> 4) << 2) + e;
            int cn = j * 16 + (lane & 15);
            float val = acc2[j][e] / sden[rl];
            ctx[((size_t)(b * L_ + zc * 64 + rl)) * 512 + h * 64 + cn] = f2b(val);
        }
}

extern "C" void kernel_launch(void* const* d_in, const int* in_sizes, int n_in,
                              void* d_out, int out_size, void* d_ws, size_t ws_size,
                              hipStream_t stream) {
    const float* query = (const float*)d_in[0];
    const float* key   = (const float*)d_in[1];
    const float* value = (const float*)d_in[2];
    const float* Wq    = (const float*)d_in[3];
    const float* bq    = (const float*)d_in[4];
    const float* Wk    = (const float*)d_in[5];
    const float* bk    = (const float*)d_in[6];
    const float* Wv    = (const float*)d_in[7];
    const float* bv    = (const float*)d_in[8];
    const float* Wout  = (const float*)d_in[9];
    const float* bout  = (const float*)d_in[10];
    const float* RF    = (const float*)d_in[11];

    char* w8 = (char*)d_ws;
    __bf16* ctx  = (__bf16*)(w8 + 0);              // 8.39MB, over dead qh
    __bf16* qh   = (__bf16*)(w8 + 0);              // [16][4096][64]
    __bf16* kh   = (__bf16*)(w8 + 8388608);
    __bf16* vT   = (__bf16*)(w8 + 16777216);       // [16][65][4096]
    __bf16* kT   = (__bf16*)(w8 + 25296896);       // [16][272][4096]
    __bf16* ScT  = (__bf16*)(w8 + 60948480);       // [64][16][65][272]
    __bf16* q_p  = (__bf16*)(w8 + 97157120);       // [16][4096][272]
    __bf16* Wqb  = (__bf16*)(w8 + 132808704);
    __bf16* Wkb  = (__bf16*)(w8 + 133332992);
    __bf16* Wvb  = (__bf16*)(w8 + 133857280);
    __bf16* Woutb= (__bf16*)(w8 + 134381568);
    __bf16* RFb  = (__bf16*)(w8 + 134905856);
    float*  hq   = (float*) (w8 + 134940672);
    float*  hk   = (float*) (w8 + 135202816);

    const float qscale = 0.21022410381342865f;     // 512^-0.25

    prep2<<<4420, 256, 0, stream>>>(Wq, Wk, Wv, Wout, RF, Wqb, Wkb, Wvb, Woutb, RFb, vT);

    dim3 gg(64, 8);
    proj<1,0><<<gg, 256, 0, stream>>>(query, Wqb, bq, qh, qscale);
    proj<1,0><<<gg, 256, 0, stream>>>(key,   Wkb, bk, kh, qscale);
    proj<1,1><<<gg, 256, 0, stream>>>(value, Wvb, bv, vT, 1.f);

    norms<<<2048, 256, 0, stream>>>(qh, kh, hq, hk);

    dim3 gr(64, 16);
    rfproj<1><<<gr, 256, 0, stream>>>(kh, RFb, hk, kT);
    rfproj<0><<<gr, 256, 0, stream>>>(qh, RFb, hq, q_p);

    chunk_sums2<<<dim3(5,1,1024), 256, 0, stream>>>(kT, vT, ScT);

    prefixk<<<1105, 256, 0, stream>>>(ScT);

    fusedD<<<1024, 256, 0, stream>>>(q_p, kT, ScT, vT, ctx);

    proj<0,2><<<gg, 256, 0, stream>>>(ctx, Woutb, bout, d_out, 1.f);
}

// Round 5
// 270.285 us; speedup vs baseline: 3.2512x; 1.2479x over previous
//
#include <hip/hip_runtime.h>
#include <hip/hip_bf16.h>

#define L_ 4096
#define MP 272            // M=266 padded to 272
#define BH16 16

typedef __attribute__((ext_vector_type(8))) __bf16 bf16x8;
typedef __attribute__((ext_vector_type(4))) float f32x4;

__device__ inline __bf16 f2b(float f) {
    unsigned u = __float_as_uint(f);
    unsigned r = (u + 0x7fffu + ((u >> 16) & 1u)) >> 16;
    unsigned short s = (unsigned short)r;
    return *reinterpret_cast<__bf16*>(&s);
}
__device__ inline float b2f(__bf16 b) {
    unsigned short s = *reinterpret_cast<unsigned short*>(&b);
    return __uint_as_float(((unsigned)s) << 16);
}

// ---------------------------------------------------------------------------
// prep2: weight casts + RF pad + vT ones row
// ---------------------------------------------------------------------------
#define NW 262144
__global__ __launch_bounds__(256) void prep2(
    const float* __restrict__ Wq, const float* __restrict__ Wk, const float* __restrict__ Wv,
    const float* __restrict__ Wout, const float* __restrict__ RF,
    __bf16* __restrict__ Wqb, __bf16* __restrict__ Wkb, __bf16* __restrict__ Wvb,
    __bf16* __restrict__ Woutb, __bf16* __restrict__ RFb, __bf16* __restrict__ vT)
{
    long idx = (long)blockIdx.x * 256 + threadIdx.x;
    if (idx < NW) { Wqb[idx] = f2b(Wq[idx]); return; }  idx -= NW;
    if (idx < NW) { Wkb[idx] = f2b(Wk[idx]); return; }  idx -= NW;
    if (idx < NW) { Wvb[idx] = f2b(Wv[idx]); return; }  idx -= NW;
    if (idx < NW) { Woutb[idx] = f2b(Wout[idx]); return; }  idx -= NW;
    if (idx < MP * 64) { int row = (int)(idx >> 6); RFb[idx] = f2b(row < 266 ? RF[idx] : 0.f); return; }
    idx -= MP * 64;
    if (idx < 65536) {
        int bh = (int)(idx >> 12), l = (int)(idx & 4095);
        vT[((size_t)bh * 65 + 64) * L_ + l] = f2b(1.f);   // ones row (den trick)
    }
}

// ---------------------------------------------------------------------------
// norms: hq/hk = -0.5*||row||^2 from bf16 qh/kh ([bh][l][64])
// ---------------------------------------------------------------------------
__global__ __launch_bounds__(256) void norms(
    const __bf16* __restrict__ qh, const __bf16* __restrict__ kh,
    float* __restrict__ hq, float* __restrict__ hk)
{
    int idx = blockIdx.x * 256 + threadIdx.x;
    int row = idx >> 2, qq = idx & 3;
    const __bf16* src = row < 65536 ? qh : kh;
    float* dst = row < 65536 ? hq : hk;
    int r = row & 65535;
    const uint4* p = (const uint4*)(src + (size_t)r * 64 + qq * 16);
    float s = 0.f;
    #pragma unroll
    for (int i = 0; i < 2; ++i) {
        uint4 u = p[i];
        unsigned arr[4] = {u.x, u.y, u.z, u.w};
        #pragma unroll
        for (int j = 0; j < 4; ++j) {
            float a = __uint_as_float(arr[j] << 16);
            float b = __uint_as_float(arr[j] & 0xffff0000u);
            s += a * a + b * b;
        }
    }
    s += __shfl_xor(s, 1);
    s += __shfl_xor(s, 2);
    if (qq == 0) dst[r] = -0.5f * s;
}

// ---------------------------------------------------------------------------
// proj: C = A @ W^T + bias. 512 threads, BM=128 BN=64, K=512, reg prefetch.
// EPI 0: qh/kh [bh][l][64]; 1: vT via LDS transpose; 2: fp32 out.
// ---------------------------------------------------------------------------
template<int AF32, int EPI>
__global__ __launch_bounds__(512) void proj(
    const void* __restrict__ Ap, const __bf16* __restrict__ W,
    const float* __restrict__ bias, void* __restrict__ O,
    float scale)
{
    __shared__ __bf16 Al[128 * 40];
    __shared__ __bf16 Bl[64 * 40];
    const int t = threadIdx.x;
    const int w = t >> 6, lane = t & 63;
    const int m0 = blockIdx.x * 128, n0 = blockIdx.y * 64;

    f32x4 acc[4];
    #pragma unroll
    for (int j = 0; j < 4; ++j) acc[j] = f32x4{0.f,0.f,0.f,0.f};

    float4 a_f[2];
    unsigned a_h[4];
    unsigned b_r[2];

    auto LOADT = [&](int ks) {
        const int kk = ks * 32;
        if constexpr (AF32) {
            const float* A = (const float*)Ap;
            #pragma unroll
            for (int it = 0; it < 2; ++it) {
                int u = t + it * 512; int r = u >> 3, q4 = (u & 7) << 2;
                a_f[it] = *(const float4*)&A[(size_t)(m0 + r) * 512 + kk + q4];
            }
        } else {
            const __bf16* A = (const __bf16*)Ap;
            #pragma unroll
            for (int it = 0; it < 4; ++it) {
                int u = t + it * 512; int r = u >> 4, dw = (u & 15) << 1;
                a_h[it] = *(const unsigned*)&A[(size_t)(m0 + r) * 512 + kk + dw];
            }
        }
        #pragma unroll
        for (int it = 0; it < 2; ++it) {
            int u = t + it * 512; int r = u >> 4, dw = (u & 15) << 1;
            b_r[it] = *(const unsigned*)&W[(size_t)(n0 + r) * 512 + kk + dw];
        }
    };
    auto STORET = [&]() {
        if constexpr (AF32) {
            #pragma unroll
            for (int it = 0; it < 2; ++it) {
                int u = t + it * 512; int r = u >> 3, q4 = (u & 7) << 2;
                __bf16* d = &Al[r * 40 + q4];
                d[0] = f2b(a_f[it].x); d[1] = f2b(a_f[it].y);
                d[2] = f2b(a_f[it].z); d[3] = f2b(a_f[it].w);
            }
        } else {
            #pragma unroll
            for (int it = 0; it < 4; ++it) {
                int u = t + it * 512; int r = u >> 4, dw = (u & 15) << 1;
                *(unsigned*)&Al[r * 40 + dw] = a_h[it];
            }
        }
        #pragma unroll
        for (int it = 0; it < 2; ++it) {
            int u = t + it * 512; int r = u >> 4, dw = (u & 15) << 1;
            *(unsigned*)&Bl[r * 40 + dw] = b_r[it];
        }
    };

    LOADT(0);
    for (int ks = 0; ks < 16; ++ks) {
        __syncthreads();
        STORET();
        __syncthreads();
        if (ks < 15) LOADT(ks + 1);
        bf16x8 af = *(const bf16x8*)&Al[(w * 16 + (lane & 15)) * 40 + (lane >> 4) * 8];
        #pragma unroll
        for (int j = 0; j < 4; ++j) {
            bf16x8 bf = *(const bf16x8*)&Bl[(j * 16 + (lane & 15)) * 40 + (lane >> 4) * 8];
            acc[j] = __builtin_amdgcn_mfma_f32_16x16x32_bf16(af, bf, acc[j], 0, 0, 0);
        }
    }

    if constexpr (EPI == 1) {
        __shared__ __bf16 Tv[64 * 136];
        #pragma unroll
        for (int j = 0; j < 4; ++j)
            #pragma unroll
            for (int e = 0; e < 4; ++e) {
                int rl = w * 16 + ((lane >> 4) << 2) + e;
                int cn = n0 + j * 16 + (lane & 15);
                Tv[(cn & 63) * 136 + rl] = f2b(acc[j][e] + bias[cn]);
            }
        __syncthreads();
        __bf16* vT = (__bf16*)O;
        int b = m0 >> 12, l0 = m0 & 4095, h = n0 >> 6;
        #pragma unroll
        for (int it = 0; it < 2; ++it) {
            int v = t + it * 512;
            int d = v >> 4, seg = v & 15;
            *(uint4*)&vT[((size_t)(b * 8 + h) * 65 + d) * L_ + l0 + seg * 8] =
                *(const uint4*)&Tv[d * 136 + seg * 8];
        }
    } else {
        #pragma unroll
        for (int j = 0; j < 4; ++j)
            #pragma unroll
            for (int e = 0; e < 4; ++e) {
                int r = m0 + w * 16 + ((lane >> 4) << 2) + e;
                int cn = n0 + j * 16 + (lane & 15);
                float val = acc[j][e];
                if constexpr (EPI == 0) {
                    float vv = (val + bias[cn]) * scale;
                    int b = r >> 12, l = r & 4095, h = cn >> 6, d = cn & 63;
                    ((__bf16*)O)[(((size_t)(b * 8 + h) * L_ + l) << 6) + d] = f2b(vv);
                } else {
                    ((float*)O)[(size_t)r * 512 + cn] = val + bias[cn];
                }
            }
    }
}

// ---------------------------------------------------------------------------
// rfproj2: per (l-block, bh, {q,k}): 64x272 tile, K=64, exp(h+val), natural out
// ---------------------------------------------------------------------------
__global__ __launch_bounds__(256) void rfproj2(
    const __bf16* __restrict__ qh, const __bf16* __restrict__ kh,
    const __bf16* __restrict__ RFb,
    const float* __restrict__ hq, const float* __restrict__ hk,
    __bf16* __restrict__ q_p, __bf16* __restrict__ k_nat)
{
    __shared__ __bf16 Al[64 * 40];
    __shared__ __bf16 Bl[MP * 40];
    const int t = threadIdx.x;
    const int w = t >> 6, lane = t & 63;
    const int l0 = blockIdx.x * 64, bh = blockIdx.y;
    const int zq = blockIdx.z;
    const __bf16* X = (zq ? kh : qh) + (size_t)bh * 262144;
    const float* hrow = (zq ? hk : hq) + (size_t)bh * 4096;
    __bf16* O = (zq ? k_nat : q_p) + (size_t)bh * 1114112;

    f32x4 acc[17];
    #pragma unroll
    for (int j = 0; j < 17; ++j) acc[j] = f32x4{0.f,0.f,0.f,0.f};

    unsigned a_r[4], b_r[17];
    auto LOADT = [&](int ks) {
        const int kk = ks * 32;
        #pragma unroll
        for (int it = 0; it < 4; ++it) {
            int u = t + it * 256; int r = u >> 4, dw = (u & 15) << 1;
            a_r[it] = *(const unsigned*)&X[(size_t)(l0 + r) * 64 + kk + dw];
        }
        #pragma unroll
        for (int it = 0; it < 17; ++it) {
            int u = t + it * 256; int r = u >> 4, dw = (u & 15) << 1;
            b_r[it] = *(const unsigned*)&RFb[(size_t)r * 64 + kk + dw];
        }
    };
    LOADT(0);
    for (int ks = 0; ks < 2; ++ks) {
        __syncthreads();
        #pragma unroll
        for (int it = 0; it < 4; ++it) {
            int u = t + it * 256; int r = u >> 4, dw = (u & 15) << 1;
            *(unsigned*)&Al[r * 40 + dw] = a_r[it];
        }
        #pragma unroll
        for (int it = 0; it < 17; ++it) {
            int u = t + it * 256; int r = u >> 4, dw = (u & 15) << 1;
            *(unsigned*)&Bl[r * 40 + dw] = b_r[it];
        }
        __syncthreads();
        if (ks < 1) LOADT(1);
        bf16x8 af = *(const bf16x8*)&Al[(w * 16 + (lane & 15)) * 40 + (lane >> 4) * 8];
        #pragma unroll
        for (int j = 0; j < 17; ++j) {
            bf16x8 bf = *(const bf16x8*)&Bl[(j * 16 + (lane & 15)) * 40 + (lane >> 4) * 8];
            acc[j] = __builtin_amdgcn_mfma_f32_16x16x32_bf16(af, bf, acc[j], 0, 0, 0);
        }
    }
    #pragma unroll
    for (int j = 0; j < 17; ++j)
        #pragma unroll
        for (int e = 0; e < 4; ++e) {
            int rl = w * 16 + ((lane >> 4) << 2) + e;
            int cn = j * 16 + (lane & 15);
            float h = hrow[l0 + rl];
            float v = (cn < 266) ? __expf(h + acc[j][e]) : 0.f;
            O[(size_t)(l0 + rl) * MP + cn] = f2b(v);
        }
}

// ---------------------------------------------------------------------------
// chunk_sums3: ScT[c*16+bh][d][m] = sum_l k'[l][m] v[l][d]; k' natural input.
// Single staging (K=64 whole), A transposed in staging.
// ---------------------------------------------------------------------------
__global__ __launch_bounds__(256) void chunk_sums3(
    const __bf16* __restrict__ k_nat, const __bf16* __restrict__ vT,
    __bf16* __restrict__ ScT)
{
    __shared__ __bf16 Al[64 * 72];   // [m_local][l]
    __shared__ __bf16 Bl[80 * 72];   // [d][l]
    __shared__ __bf16 T2[80 * 72];   // [d][m_local]
    const int t = threadIdx.x;
    const int w = t >> 6, lane = t & 63;
    const int m0 = blockIdx.x * 64;
    const int z = blockIdx.z, zb = z & 15, zc = z >> 4;
    const __bf16* A = k_nat + (size_t)zb * 1114112 + (size_t)(zc * 64) * MP;
    const __bf16* B = vT + (size_t)zb * 266240 + (size_t)zc * 64;

    #pragma unroll
    for (int it = 0; it < 8; ++it) {
        int u = t + it * 256; int l = u >> 5, mp = (u & 31) << 1;
        unsigned v = (m0 + mp < MP) ? *(const unsigned*)&A[(size_t)l * MP + m0 + mp] : 0u;
        unsigned short lo = (unsigned short)(v & 0xffffu), hi = (unsigned short)(v >> 16);
        Al[mp * 72 + l] = *reinterpret_cast<__bf16*>(&lo);
        Al[(mp + 1) * 72 + l] = *reinterpret_cast<__bf16*>(&hi);
    }
    #pragma unroll
    for (int it = 0; it < 10; ++it) {
        int u = t + it * 256; int d = u >> 5, lp = (u & 31) << 1;
        unsigned v = (d < 65) ? *(const unsigned*)&B[(size_t)d * L_ + lp] : 0u;
        *(unsigned*)&Bl[d * 72 + lp] = v;
    }
    __syncthreads();
    f32x4 acc[5];
    #pragma unroll
    for (int j = 0; j < 5; ++j) acc[j] = f32x4{0.f,0.f,0.f,0.f};
    #pragma unroll
    for (int ks = 0; ks < 2; ++ks) {
        const int kk = ks * 32;
        bf16x8 af = *(const bf16x8*)&Al[(w * 16 + (lane & 15)) * 72 + kk + (lane >> 4) * 8];
        #pragma unroll
        for (int j = 0; j < 5; ++j) {
            bf16x8 bf = *(const bf16x8*)&Bl[(j * 16 + (lane & 15)) * 72 + kk + (lane >> 4) * 8];
            acc[j] = __builtin_amdgcn_mfma_f32_16x16x32_bf16(af, bf, acc[j], 0, 0, 0);
        }
    }
    #pragma unroll
    for (int j = 0; j < 5; ++j)
        #pragma unroll
        for (int e = 0; e < 4; ++e) {
            int rl = w * 16 + ((lane >> 4) << 2) + e;   // m_local
            int cn = j * 16 + (lane & 15);              // d
            T2[cn * 72 + rl] = f2b(acc[j][e]);
        }
    __syncthreads();
    __bf16* Obase = ScT + (size_t)(zc * 16 + zb) * 17680;
    for (int v2 = t; v2 < 65 * 8; v2 += 256) {
        int row = v2 >> 3, seg = v2 & 7;
        if (m0 + seg * 8 < MP)
            *(uint4*)&Obase[(size_t)row * MP + m0 + seg * 8] = *(const uint4*)&T2[row * 72 + seg * 8];
    }
}

// ---------------------------------------------------------------------------
// exclusive prefix over chunks, batched loads (8 in flight)
// ---------------------------------------------------------------------------
__global__ __launch_bounds__(256) void prefixk(__bf16* __restrict__ ScT)
{
    int idx = blockIdx.x * 256 + threadIdx.x;
    const int STRIDE = BH16 * 65 * MP;   // 282880
    if (idx >= STRIDE) return;
    __bf16* p = ScT + idx;
    float run = 0.f;
    #pragma unroll 1
    for (int cb = 0; cb < 8; ++cb) {
        float v[8];
        #pragma unroll
        for (int i = 0; i < 8; ++i) v[i] = b2f(p[(size_t)(cb * 8 + i) * STRIDE]);
        #pragma unroll
        for (int i = 0; i < 8; ++i) { p[(size_t)(cb * 8 + i) * STRIDE] = f2b(run); run += v[i]; }
    }
}

// ---------------------------------------------------------------------------
// fusedD: per (c,bh): S=tril(q'k'^T); acc2 = q'@Sp^T + S@Vext; ctx = num/den
// k' natural layout; reg-prefetch double buffer; V preloaded.
// ---------------------------------------------------------------------------
__global__ __launch_bounds__(256) void fusedD(
    const __bf16* __restrict__ q_p, const __bf16* __restrict__ k_nat,
    const __bf16* __restrict__ ScT, const __bf16* __restrict__ vT,
    __bf16* __restrict__ ctx)
{
    __shared__ __bf16 Aq[64 * 40];
    __shared__ __bf16 B1l[64 * 40];
    __shared__ __bf16 B2l[80 * 40];
    __shared__ __bf16 Vl[80 * 72];
    __shared__ __bf16 Sl[64 * 72];
    __shared__ float sden[64];
    const int t = threadIdx.x;
    const int w = t >> 6, lane = t & 63;
    const int z = blockIdx.x, zb = z & 15, zc = z >> 4;
    const __bf16* qp_b = q_p + (size_t)zb * 1114112 + (size_t)(zc * 64) * MP;
    const __bf16* kn_b = k_nat + (size_t)zb * 1114112 + (size_t)(zc * 64) * MP;
    const __bf16* Sp_b = ScT + (size_t)(zc * 16 + zb) * 17680;
    const __bf16* vT_b = vT + (size_t)zb * 266240 + (size_t)zc * 64;

    // V preload (held in regs through phase 1)
    unsigned v_r[10];
    #pragma unroll
    for (int it = 0; it < 10; ++it) {
        int u = t + it * 256; int d = u >> 5, lp = (u & 31) << 1;
        v_r[it] = (d < 65) ? *(const unsigned*)&vT_b[(size_t)d * L_ + lp] : 0u;
    }

    unsigned a_r[4], b_r[4], c_r[5];
    auto LOADT = [&](int ks) {
        const int kk = ks * 32;
        #pragma unroll
        for (int it = 0; it < 4; ++it) {
            int u = t + it * 256; int r = u >> 4, dw = (u & 15) << 1;
            bool ok = (kk + dw) < MP;
            a_r[it] = ok ? *(const unsigned*)&qp_b[(size_t)r * MP + kk + dw] : 0u;
            b_r[it] = ok ? *(const unsigned*)&kn_b[(size_t)r * MP + kk + dw] : 0u;
        }
        #pragma unroll
        for (int it = 0; it < 5; ++it) {
            int u = t + it * 256; int r = u >> 4, dw = (u & 15) << 1;
            c_r[it] = (r < 65 && (kk + dw) < MP) ? *(const unsigned*)&Sp_b[(size_t)r * MP + kk + dw] : 0u;
        }
    };

    f32x4 acc1[4], acc2[5];
    #pragma unroll
    for (int j = 0; j < 4; ++j) acc1[j] = f32x4{0.f,0.f,0.f,0.f};
    #pragma unroll
    for (int j = 0; j < 5; ++j) acc2[j] = f32x4{0.f,0.f,0.f,0.f};

    LOADT(0);
    for (int ks = 0; ks < 9; ++ks) {
        __syncthreads();
        #pragma unroll
        for (int it = 0; it < 4; ++it) {
            int u = t + it * 256; int r = u >> 4, dw = (u & 15) << 1;
            *(unsigned*)&Aq[r * 40 + dw] = a_r[it];
            *(unsigned*)&B1l[r * 40 + dw] = b_r[it];
        }
        #pragma unroll
        for (int it = 0; it < 5; ++it) {
            int u = t + it * 256; int r = u >> 4, dw = (u & 15) << 1;
            *(unsigned*)&B2l[r * 40 + dw] = c_r[it];
        }
        __syncthreads();
        if (ks < 8) LOADT(ks + 1);
        bf16x8 af = *(const bf16x8*)&Aq[(w * 16 + (lane & 15)) * 40 + (lane >> 4) * 8];
        #pragma unroll
        for (int j = 0; j < 4; ++j) {
            bf16x8 bf = *(const bf16x8*)&B1l[(j * 16 + (lane & 15)) * 40 + (lane >> 4) * 8];
            acc1[j] = __builtin_amdgcn_mfma_f32_16x16x32_bf16(af, bf, acc1[j], 0, 0, 0);
        }
        #pragma unroll
        for (int j = 0; j < 5; ++j) {
            bf16x8 bf = *(const bf16x8*)&B2l[(j * 16 + (lane & 15)) * 40 + (lane >> 4) * 8];
            acc2[j] = __builtin_amdgcn_mfma_f32_16x16x32_bf16(af, bf, acc2[j], 0, 0, 0);
        }
    }
    // Vl + masked S -> LDS
    #pragma unroll
    for (int it = 0; it < 10; ++it) {
        int u = t + it * 256; int d = u >> 5, lp = (u & 31) << 1;
        *(unsigned*)&Vl[d * 72 + lp] = v_r[it];
    }
    #pragma unroll
    for (int j = 0; j < 4; ++j)
        #pragma unroll
        for (int e = 0; e < 4; ++e) {
            int rl = w * 16 + ((lane >> 4) << 2) + e;
            int cn = j * 16 + (lane & 15);
            Sl[rl * 72 + cn] = f2b(rl >= cn ? acc1[j][e] : 0.f);
        }
    __syncthreads();
    // phase 3: acc2 += S @ Vext (LDS-resident)
    #pragma unroll
    for (int ks2 = 0; ks2 < 2; ++ks2) {
        const int kk = ks2 * 32;
        bf16x8 as = *(const bf16x8*)&Sl[(w * 16 + (lane & 15)) * 72 + kk + (lane >> 4) * 8];
        #pragma unroll
        for (int j = 0; j < 5; ++j) {
            bf16x8 bf = *(const bf16x8*)&Vl[(j * 16 + (lane & 15)) * 72 + kk + (lane >> 4) * 8];
            acc2[j] = __builtin_amdgcn_mfma_f32_16x16x32_bf16(as, bf, acc2[j], 0, 0, 0);
        }
    }
    // den broadcast (col 64 of acc2[4])
    if ((lane & 15) == 0) {
        #pragma unroll
        for (int e = 0; e < 4; ++e)
            sden[w * 16 + ((lane >> 4) << 2) + e] = acc2[4][e];
    }
    __syncthreads();
    const int b = zb >> 3, h = zb & 7;
    #pragma unroll
    for (int j = 0; j < 4; ++j)
        #pragma unroll
        for (int e = 0; e < 4; ++e) {
            int rl = w * 16 + ((lane >> 4) << 2) + e;
            int cn = j * 16 + (lane & 15);
            float val = acc2[j][e] / sden[rl];
            ctx[((size_t)(b * L_ + zc * 64 + rl)) * 512 + h * 64 + cn] = f2b(val);
        }
}

extern "C" void kernel_launch(void* const* d_in, const int* in_sizes, int n_in,
                              void* d_out, int out_size, void* d_ws, size_t ws_size,
                              hipStream_t stream) {
    const float* query = (const float*)d_in[0];
    const float* key   = (const float*)d_in[1];
    const float* value = (const float*)d_in[2];
    const float* Wq    = (const float*)d_in[3];
    const float* bq    = (const float*)d_in[4];
    const float* Wk    = (const float*)d_in[5];
    const float* bk    = (const float*)d_in[6];
    const float* Wv    = (const float*)d_in[7];
    const float* bv    = (const float*)d_in[8];
    const float* Wout  = (const float*)d_in[9];
    const float* bout  = (const float*)d_in[10];
    const float* RF    = (const float*)d_in[11];

    char* w8 = (char*)d_ws;
    __bf16* ctx  = (__bf16*)(w8 + 0);              // over dead qh
    __bf16* qh   = (__bf16*)(w8 + 0);              // [16][4096][64]
    __bf16* kh   = (__bf16*)(w8 + 8388608);
    __bf16* vT   = (__bf16*)(w8 + 16777216);       // [16][65][4096]
    __bf16* k_nat= (__bf16*)(w8 + 25296896);       // [16][4096][272]
    __bf16* ScT  = (__bf16*)(w8 + 60948480);       // [64][16][65][272]
    __bf16* q_p  = (__bf16*)(w8 + 97157120);       // [16][4096][272]
    __bf16* Wqb  = (__bf16*)(w8 + 132808704);
    __bf16* Wkb  = (__bf16*)(w8 + 133332992);
    __bf16* Wvb  = (__bf16*)(w8 + 133857280);
    __bf16* Woutb= (__bf16*)(w8 + 134381568);
    __bf16* RFb  = (__bf16*)(w8 + 134905856);
    float*  hq   = (float*) (w8 + 134940672);
    float*  hk   = (float*) (w8 + 135202816);

    const float qscale = 0.21022410381342865f;     // 512^-0.25

    prep2<<<4420, 256, 0, stream>>>(Wq, Wk, Wv, Wout, RF, Wqb, Wkb, Wvb, Woutb, RFb, vT);

    dim3 gg(64, 8);
    proj<1,0><<<gg, 512, 0, stream>>>(query, Wqb, bq, qh, qscale);
    proj<1,0><<<gg, 512, 0, stream>>>(key,   Wkb, bk, kh, qscale);
    proj<1,1><<<gg, 512, 0, stream>>>(value, Wvb, bv, vT, 1.f);

    norms<<<2048, 256, 0, stream>>>(qh, kh, hq, hk);

    rfproj2<<<dim3(64,16,2), 256, 0, stream>>>(qh, kh, RFb, hq, hk, q_p, k_nat);

    chunk_sums3<<<dim3(5,1,1024), 256, 0, stream>>>(k_nat, vT, ScT);

    prefixk<<<1105, 256, 0, stream>>>(ScT);

    fusedD<<<1024, 256, 0, stream>>>(q_p, k_nat, ScT, vT, ctx);

    proj<0,2><<<gg, 512, 0, stream>>>(ctx, Woutb, bout, d_out, 1.f);
}